// Round 1
// baseline (990.270 us; speedup 1.0000x reference)
//
#include <hip/hip_runtime.h>
#include <hip/hip_bf16.h>

// Problem constants
#define TT_  8
#define HH_  64
#define WW_  64
#define CC_  256
#define HEADS_ 8
#define HD_  32
#define WS_  7
#define NB_  147              // 3 * 49
#define NPIX (TT_*HH_*WW_)    // 32768
#define NTASK (NPIX*NB_)      // 4,816,896

typedef _Float16 half8 __attribute__((ext_vector_type(8)));
typedef _Float16 h2    __attribute__((ext_vector_type(2)));
typedef float    f32x4 __attribute__((ext_vector_type(4)));

__device__ __forceinline__ half8 load_cvt8(const float* __restrict__ p) {
  float4 a = ((const float4*)p)[0];
  float4 b = ((const float4*)p)[1];
  half8 h;
  h[0]=(_Float16)a.x; h[1]=(_Float16)a.y; h[2]=(_Float16)a.z; h[3]=(_Float16)a.w;
  h[4]=(_Float16)b.x; h[5]=(_Float16)b.y; h[6]=(_Float16)b.z; h[7]=(_Float16)b.w;
  return h;
}

// -------- Kernel 1: qk = x @ W_qk^T, store q,k as f16 into workspace --------
// M = 32768, N = 512, K = 256.  Block tile 128x128 (4 waves, 64x64/wave).
__global__ __launch_bounds__(256) void qk_gemm(
    const float* __restrict__ x, const float* __restrict__ wqk,
    _Float16* __restrict__ qws, _Float16* __restrict__ kws) {
  int bid  = blockIdx.x;
  int mblk = bid >> 2;          // 256 m-blocks
  int nblk = bid & 3;           // 4 n-blocks
  int lane = threadIdx.x & 63;
  int wv   = threadIdx.x >> 6;
  int m0 = mblk * 128 + (wv >> 1) * 64;
  int n0 = nblk * 128 + (wv & 1) * 64;
  int r    = lane & 15;
  int quad = lane >> 4;

  f32x4 acc[4][4] = {};

  for (int k0 = 0; k0 < 256; k0 += 32) {
    int kk = k0 + quad * 8;
    half8 afr[4], bfr[4];
#pragma unroll
    for (int im = 0; im < 4; im++)
      afr[im] = load_cvt8(x + (size_t)(m0 + im*16 + r) * 256 + kk);
#pragma unroll
    for (int in = 0; in < 4; in++)
      bfr[in] = load_cvt8(wqk + (size_t)(n0 + in*16 + r) * 256 + kk);
#pragma unroll
    for (int im = 0; im < 4; im++)
#pragma unroll
      for (int in = 0; in < 4; in++)
        acc[im][in] = __builtin_amdgcn_mfma_f32_16x16x32_f16(
            afr[im], bfr[in], acc[im][in], 0, 0, 0);
  }

  // Epilogue: D[m][n], col n = r, row m = quad*4 + reg within each 16x16 tile.
  // cols 0..255 -> q (head = n/32, hd = n%32), cols 256..511 -> k.
#pragma unroll
  for (int im = 0; im < 4; im++) {
#pragma unroll
    for (int in = 0; in < 4; in++) {
      int n = n0 + in*16 + r;
#pragma unroll
      for (int reg = 0; reg < 4; reg++) {
        int m = m0 + im*16 + quad*4 + reg;
        _Float16 hv = (_Float16)acc[im][in][reg];
        if (n < 256) qws[(size_t)m*256 + n]       = hv;
        else         kws[(size_t)m*256 + (n-256)] = hv;
      }
    }
  }
}

// -------- Kernel 2: neighborhood attention scores + offset tensor --------
__device__ __forceinline__ int reflect64(int v) {
  int m = v % 126;
  m += (m >> 31) & 126;          // floor-mod into [0,126)
  return (m > 63) ? (126 - m) : m;
}

__device__ __forceinline__ float dot2f(h2 a, h2 b, float c) {
#if __has_builtin(__builtin_amdgcn_fdot2)
  return __builtin_amdgcn_fdot2(a, b, c, false);
#else
  return c + (float)a[0]*(float)b[0] + (float)a[1]*(float)b[1];
#endif
}

__global__ __launch_bounds__(256) void attn_kernel(
    const float* __restrict__ flows,
    const _Float16* __restrict__ qws, const _Float16* __restrict__ kws,
    float* __restrict__ out) {
  // XCD swizzle: gridDim.x = 18816 = 8*2352; contiguous task range per XCD
  // => XCD c handles exactly frame t=c (k working set ~3 frames ~6MB).
  int nbq  = (int)gridDim.x >> 3;
  int nb2  = ((int)blockIdx.x & 7) * nbq + ((int)blockIdx.x >> 3);
  int tid  = nb2 * 256 + (int)threadIdx.x;
  if (tid >= NTASK) return;

  unsigned p  = (unsigned)tid / 147u;       // pixel
  int      nb = tid - (int)(p * 147u);      // neighbor slot index 0..146
  int t = (int)(p >> 12);
  int hw = (int)(p & 4095u);
  int h = hw >> 6, w = hw & 63;
  int slot = nb / 49;
  int rr = nb - slot * 49;
  int a  = rr / 7;
  int b  = rr - a * 7;

  int tp = t, di = 0, dj = 0;
  if (slot > 0) {
    int si = slot - 1;
    float fi = flows[(size_t)((t*2 + si)*2 + 0) * 4096 + hw];
    float fj = flows[(size_t)((t*2 + si)*2 + 1) * 4096 + hw];
    di = (int)rintf(fi);                    // RTNE == jnp.round
    dj = (int)rintf(fj);
    tp = (slot == 1) ? ((t + 1 < TT_) ? t + 1 : t - 2)
                     : ((t - 1 >= 0)  ? t - 1 : t + 2);
  }
  int li = reflect64(h + di + a - 3);
  int lj = reflect64(w + dj + b - 3);

  float fdt = (float)(tp - t);
  float foi = (float)(li - h);
  float foj = (float)(lj - w);

  const _Float16* kv = kws + ((size_t)((tp << 12) + (li << 6) + lj)) * 256;
  const _Float16* qv = qws + (size_t)p * 256;
  const float scale = 0.17677669529663687f;   // 32^-0.5

  float sc[8];
#pragma unroll
  for (int head = 0; head < 8; head++) {
    const half8* kp = (const half8*)(kv + head * 32);
    const half8* qp = (const half8*)(qv + head * 32);
    float s = 0.f;
#pragma unroll
    for (int i = 0; i < 4; i++) {
      half8 k8 = kp[i];
      half8 q8 = qp[i];
#pragma unroll
      for (int j = 0; j < 8; j += 2) {
        h2 ka = { k8[j], k8[j+1] };
        h2 qa = { q8[j], q8[j+1] };
        s = dot2f(ka, qa, s);
      }
    }
    sc[head] = s * scale;
  }

  // attn[0][head][t][h][w][nb]  ->  head*NTASK + tid  (fully coalesced)
#pragma unroll
  for (int head = 0; head < 8; head++)
    out[(size_t)head * NTASK + tid] = sc[head];

  // flows_k[0][head][t][h][w][nb][3] (int values written as float)
  float* fo = out + (size_t)HEADS_ * NTASK;
#pragma unroll
  for (int head = 0; head < 8; head++) {
    size_t base = (size_t)head * NTASK * 3 + (size_t)tid * 3;
    fo[base + 0] = fdt;
    fo[base + 1] = foi;
    fo[base + 2] = foj;
  }
}

extern "C" void kernel_launch(void* const* d_in, const int* in_sizes, int n_in,
                              void* d_out, int out_size, void* d_ws, size_t ws_size,
                              hipStream_t stream) {
  const float* x     = (const float*)d_in[0];   // (8,64,64,256) f32
  const float* flows = (const float*)d_in[1];   // (1,8,2,2,64,64) f32
  const float* wqk   = (const float*)d_in[2];   // (512,256) f32
  float* out = (float*)d_out;

  _Float16* qws = (_Float16*)d_ws;                       // 32768*256 f16
  _Float16* kws = qws + (size_t)NPIX * 256;              // 32768*256 f16

  qk_gemm<<<dim3(1024), dim3(256), 0, stream>>>(x, wqk, qws, kws);
  attn_kernel<<<dim3(NTASK / 256), dim3(256), 0, stream>>>(flows, qws, kws, out);
}

// Round 2
// 837.223 us; speedup vs baseline: 1.1828x; 1.1828x over previous
//
#include <hip/hip_runtime.h>
#include <hip/hip_bf16.h>

// Problem constants
#define TT_  8
#define HH_  64
#define WW_  64
#define CC_  256
#define HEADS_ 8
#define HD_  32
#define WS_  7
#define NB_  147              // 3 * 49
#define NPIX (TT_*HH_*WW_)    // 32768
#define NTASK (NPIX*NB_)      // 4,816,896

typedef _Float16 half8 __attribute__((ext_vector_type(8)));
typedef _Float16 h2    __attribute__((ext_vector_type(2)));
typedef float    f32x4 __attribute__((ext_vector_type(4)));

__device__ __forceinline__ half8 load_cvt8(const float* __restrict__ p) {
  float4 a = ((const float4*)p)[0];
  float4 b = ((const float4*)p)[1];
  half8 h;
  h[0]=(_Float16)a.x; h[1]=(_Float16)a.y; h[2]=(_Float16)a.z; h[3]=(_Float16)a.w;
  h[4]=(_Float16)b.x; h[5]=(_Float16)b.y; h[6]=(_Float16)b.z; h[7]=(_Float16)b.w;
  return h;
}

// -------- Kernel 1: qk = x @ W_qk^T, store q,k as f16 into workspace --------
// M = 32768, N = 512, K = 256.  Block tile 128x128 (4 waves, 64x64/wave).
__global__ __launch_bounds__(256) void qk_gemm(
    const float* __restrict__ x, const float* __restrict__ wqk,
    _Float16* __restrict__ qws, _Float16* __restrict__ kws) {
  int bid  = blockIdx.x;
  int mblk = bid >> 2;          // 256 m-blocks
  int nblk = bid & 3;           // 4 n-blocks
  int lane = threadIdx.x & 63;
  int wv   = threadIdx.x >> 6;
  int m0 = mblk * 128 + (wv >> 1) * 64;
  int n0 = nblk * 128 + (wv & 1) * 64;
  int r    = lane & 15;
  int quad = lane >> 4;

  f32x4 acc[4][4] = {};

  for (int k0 = 0; k0 < 256; k0 += 32) {
    int kk = k0 + quad * 8;
    half8 afr[4], bfr[4];
#pragma unroll
    for (int im = 0; im < 4; im++)
      afr[im] = load_cvt8(x + (size_t)(m0 + im*16 + r) * 256 + kk);
#pragma unroll
    for (int in = 0; in < 4; in++)
      bfr[in] = load_cvt8(wqk + (size_t)(n0 + in*16 + r) * 256 + kk);
#pragma unroll
    for (int im = 0; im < 4; im++)
#pragma unroll
      for (int in = 0; in < 4; in++)
        acc[im][in] = __builtin_amdgcn_mfma_f32_16x16x32_f16(
            afr[im], bfr[in], acc[im][in], 0, 0, 0);
  }

  // Epilogue: D[m][n], col n = r, row m = quad*4 + reg within each 16x16 tile.
#pragma unroll
  for (int im = 0; im < 4; im++) {
#pragma unroll
    for (int in = 0; in < 4; in++) {
      int n = n0 + in*16 + r;
#pragma unroll
      for (int reg = 0; reg < 4; reg++) {
        int m = m0 + im*16 + quad*4 + reg;
        _Float16 hv = (_Float16)acc[im][in][reg];
        if (n < 256) qws[(size_t)m*256 + n]       = hv;
        else         kws[(size_t)m*256 + (n-256)] = hv;
      }
    }
  }
}

// -------- Kernel 2: neighborhood attention, 8 lanes cooperate per task ------
__device__ __forceinline__ int reflect64(int v) {
  int m = v % 126;
  m += (m >> 31) & 126;          // floor-mod into [0,126)
  return (m > 63) ? (126 - m) : m;
}

__device__ __forceinline__ float dot2f(h2 a, h2 b, float c) {
#if __has_builtin(__builtin_amdgcn_fdot2)
  return __builtin_amdgcn_fdot2(a, b, c, false);
#else
  return c + (float)a[0]*(float)b[0] + (float)a[1]*(float)b[1];
#endif
}

__global__ __launch_bounds__(256) void attn_kernel(
    const float* __restrict__ flows,
    const _Float16* __restrict__ qws, const _Float16* __restrict__ kws,
    float* __restrict__ out) {
  // Block handles 32 consecutive tasks (4 waves x 8 tasks, 8 lanes/task).
  __shared__ float s_attn[8][32];   // [head][task-in-block]
  __shared__ float s_flow[32][3];   // [task-in-block][component]

  // XCD swizzle: grid = 150528 = 8 * 18816; XCD c gets frame t=c contiguous.
  int nbq  = (int)gridDim.x >> 3;
  int nb2  = ((int)blockIdx.x & 7) * nbq + ((int)blockIdx.x >> 3);
  int tx   = (int)threadIdx.x;
  int lane = tx & 63;
  int wv   = tx >> 6;
  int w    = lane >> 3;          // task within wave, 0..7
  int j    = lane & 7;           // lane within task
  int btid0 = nb2 * 32;          // block's first task
  int tid   = btid0 + wv * 8 + w;

  unsigned p  = (unsigned)tid / 147u;       // pixel
  int      nb = tid - (int)(p * 147u);      // neighbor index 0..146
  int t  = (int)(p >> 12);
  int hw = (int)(p & 4095u);
  int h  = hw >> 6, wcol = hw & 63;
  int slot = nb / 49;
  int rr = nb - slot * 49;
  int a  = rr / 7;
  int b  = rr - a * 7;

  int tp = t, di = 0, dj = 0;
  if (slot > 0) {
    int si = slot - 1;
    float fi = flows[(size_t)((t*2 + si)*2 + 0) * 4096 + hw];
    float fj = flows[(size_t)((t*2 + si)*2 + 1) * 4096 + hw];
    di = (int)rintf(fi);                    // RTNE == jnp.round
    dj = (int)rintf(fj);
    tp = (slot == 1) ? ((t + 1 < TT_) ? t + 1 : t - 2)
                     : ((t - 1 >= 0)  ? t - 1 : t + 2);
  }
  int li = reflect64(h + di + a - 3);
  int lj = reflect64(wcol + dj + b - 3);

  const _Float16* kv = kws + ((size_t)((tp << 12) + (li << 6) + lj)) * 256;
  const _Float16* qv = qws + (size_t)p * 256;

  // Lane j loads bytes [i*128 + j*16) of the 512B vectors: consecutive lanes
  // -> consecutive 16B -> fully coalesced gather (8 x 128B segments / inst).
  // Chunk i on lane j covers elements [i*64 + j*8, +8) -> head 2i + (j>>2).
  float part[4];
#pragma unroll
  for (int i = 0; i < 4; i++) {
    half8 k8 = *(const half8*)(kv + i*64 + j*8);
    half8 q8 = *(const half8*)(qv + i*64 + j*8);
    float s = 0.f;
#pragma unroll
    for (int u = 0; u < 8; u += 2) {
      h2 ka = { k8[u], k8[u+1] };
      h2 qa = { q8[u], q8[u+1] };
      s = dot2f(ka, qa, s);
    }
    part[i] = s;
  }
  // Reduce over the 4 lanes sharing (j>>2): head 2i+(j>>2) complete dot.
#pragma unroll
  for (int i = 0; i < 4; i++) {
    part[i] += __shfl_xor(part[i], 1);
    part[i] += __shfl_xor(part[i], 2);
  }

  const float scale = 0.17677669529663687f;   // 32^-0.5
  int tib = wv * 8 + w;                       // task in block, 0..31
  if ((j & 3) == 0) {
    int hb = j >> 2;
#pragma unroll
    for (int i = 0; i < 4; i++)
      s_attn[2*i + hb][tib] = part[i] * scale;
  }
  if (j < 3) {
    float v = (j == 0) ? (float)(tp - t)
            : (j == 1) ? (float)(li - h)
                       : (float)(lj - wcol);
    s_flow[tib][j] = v;
  }
  __syncthreads();

  // attn[0][head][pixel][nb] -> head*NTASK + task; block covers 32 tasks.
  out[(size_t)(tx >> 5) * NTASK + btid0 + (tx & 31)] = s_attn[tx >> 5][tx & 31];

  // flows_k[0][head][pixel][nb][3]
  float* fo = out + (size_t)HEADS_ * NTASK;
#pragma unroll
  for (int s = 0; s < 3; s++) {
    int f   = s * 256 + tx;        // 0..767 = head*96 + task*3 + c
    int hh  = f / 96;
    int rem = f - hh * 96;
    int ww  = rem / 3;
    int c   = rem - ww * 3;
    fo[(size_t)hh * NTASK * 3 + (size_t)btid0 * 3 + rem] = s_flow[ww][c];
  }
}

extern "C" void kernel_launch(void* const* d_in, const int* in_sizes, int n_in,
                              void* d_out, int out_size, void* d_ws, size_t ws_size,
                              hipStream_t stream) {
  const float* x     = (const float*)d_in[0];   // (8,64,64,256) f32
  const float* flows = (const float*)d_in[1];   // (1,8,2,2,64,64) f32
  const float* wqk   = (const float*)d_in[2];   // (512,256) f32
  float* out = (float*)d_out;

  _Float16* qws = (_Float16*)d_ws;                       // 32768*256 f16
  _Float16* kws = qws + (size_t)NPIX * 256;              // 32768*256 f16

  qk_gemm<<<dim3(1024), dim3(256), 0, stream>>>(x, wqk, qws, kws);
  attn_kernel<<<dim3(NTASK / 32), dim3(256), 0, stream>>>(flows, qws, kws, out);
}

// Round 3
// 767.665 us; speedup vs baseline: 1.2900x; 1.0906x over previous
//
#include <hip/hip_runtime.h>
#include <hip/hip_bf16.h>

#define TT_    8
#define HEADS_ 8
#define NB_    147
#define NPIX   32768                // 8*64*64
#define NTASK  (NPIX*NB_)           // 4,816,896
#define ROWS_  (NPIX + 512)         // x rows + W rows, concatenated for prepack

typedef _Float16 half8 __attribute__((ext_vector_type(8)));
typedef _Float16 h2    __attribute__((ext_vector_type(2)));
typedef float    f32x4 __attribute__((ext_vector_type(4)));

__device__ __forceinline__ int reflect64(int v) {
  int m = v % 126;
  m += (m >> 31) & 126;             // floor-mod into [0,126)
  return (m > 63) ? (126 - m) : m;
}

__device__ __forceinline__ float dot2f(h2 a, h2 b, float c) {
#if __has_builtin(__builtin_amdgcn_fdot2)
  return __builtin_amdgcn_fdot2(a, b, c, false);
#else
  return c + (float)a[0]*(float)b[0] + (float)a[1]*(float)b[1];
#endif
}

// ---- Kernel 0: prepack x||W (rows x 256 f32) into fragment-native f16 ----
// 16B chunk id o: r=o&15, quad=(o>>4)&3, ks=(o>>6)&7, mt=o>>9.
// Chunk holds row (mt*16+r), cols [(ks*4+quad)*8, +8) as f16.
__global__ __launch_bounds__(256) void prepack(
    const float* __restrict__ x, const float* __restrict__ wqk,
    _Float16* __restrict__ outp) {
  int o  = (int)blockIdx.x * 256 + (int)threadIdx.x;   // 0 .. ROWS_*32
  int r  = o & 15, quad = (o >> 4) & 3, ks = (o >> 6) & 7, mt = o >> 9;
  int row = mt * 16 + r;
  const float* src = (row < NPIX) ? (x + (size_t)row * 256)
                                  : (wqk + (size_t)(row - NPIX) * 256);
  int col = (ks * 4 + quad) * 8;
  float4 a = *(const float4*)(src + col);
  float4 b = *(const float4*)(src + col + 4);
  half8 h;
  h[0]=(_Float16)a.x; h[1]=(_Float16)a.y; h[2]=(_Float16)a.z; h[3]=(_Float16)a.w;
  h[4]=(_Float16)b.x; h[5]=(_Float16)b.y; h[6]=(_Float16)b.z; h[7]=(_Float16)b.w;
  ((half8*)outp)[o] = h;
}

// ---- Kernel 1: qk GEMM from prepacked fragments (no LDS) ----
// grid 4096: mblk = bid>>3 (64-row m-tile), nblk = bid&7 (64-col n-tile).
// 4 waves: 32x32 each. All fragments register-resident, loads fully coalesced.
__global__ __launch_bounds__(256) void qk_gemm(
    const _Float16* __restrict__ Ap,
    _Float16* __restrict__ qws, _Float16* __restrict__ kws) {
  const half8* A8 = (const half8*)Ap;
  const half8* B8 = (const half8*)(Ap + (size_t)NPIX * 256);
  int bid  = (int)blockIdx.x;
  int mblk = bid >> 3, nblk = bid & 7;
  int lane = (int)threadIdx.x & 63, wv = (int)threadIdx.x >> 6;
  int wm = mblk * 64 + (wv >> 1) * 32;
  int wn = nblk * 64 + (wv & 1) * 32;
  int r = lane & 15, quad = lane >> 4;

  half8 af[2][8], bf[2][8];
#pragma unroll
  for (int im = 0; im < 2; im++) {
    int mt = (wm >> 4) + im;
#pragma unroll
    for (int ks = 0; ks < 8; ks++)
      af[im][ks] = A8[((mt * 8 + ks) * 4 + quad) * 16 + r];
  }
#pragma unroll
  for (int in = 0; in < 2; in++) {
    int nt = (wn >> 4) + in;
#pragma unroll
    for (int ks = 0; ks < 8; ks++)
      bf[in][ks] = B8[((nt * 8 + ks) * 4 + quad) * 16 + r];
  }

  f32x4 acc[2][2] = {};
#pragma unroll
  for (int ks = 0; ks < 8; ks++)
#pragma unroll
    for (int im = 0; im < 2; im++)
#pragma unroll
      for (int in = 0; in < 2; in++)
        acc[im][in] = __builtin_amdgcn_mfma_f32_16x16x32_f16(
            af[im][ks], bf[in][ks], acc[im][in], 0, 0, 0);

  // n-block is uniformly q (nblk<4) or k: no divergence.
  _Float16* dst = (wn < 256) ? qws : kws;
  int nsub = (wn < 256) ? 0 : 256;
#pragma unroll
  for (int im = 0; im < 2; im++)
#pragma unroll
    for (int in = 0; in < 2; in++) {
      int n = wn + in * 16 + r - nsub;
#pragma unroll
      for (int reg = 0; reg < 4; reg++) {
        int m = wm + im * 16 + quad * 4 + reg;
        dst[(size_t)m * 256 + n] = (_Float16)acc[im][in][reg];
      }
    }
}

// ---- Kernel 2: neighborhood attention ----
// Block = 256 tasks. Phase 1: one thread per task computes setup -> LDS.
// Phase 2: 8 lanes per task, lane j = head j, full dot per lane, no shuffles.
__global__ __launch_bounds__(256) void attn_kernel(
    const float* __restrict__ flows,
    const _Float16* __restrict__ qws, const _Float16* __restrict__ kws,
    float* __restrict__ out) {
  __shared__ int      s_info[256];
  __shared__ __attribute__((aligned(16))) _Float16 s_q[3 * 4 * 8 * 8]; // [pix][c][j][8]
  __shared__ __attribute__((aligned(16))) float    s_attn[8 * 260];    // [head][task], pad 260
  __shared__ __attribute__((aligned(16))) float    s_flow[768];        // [task*3+c]

  // XCD swizzle: grid 18816 = 8*2352, contiguous task range per XCD.
  int nbq = (int)gridDim.x >> 3;
  int blk = ((int)blockIdx.x & 7) * nbq + ((int)blockIdx.x >> 3);
  int tx  = (int)threadIdx.x;
  int btid0 = blk * 256;
  int p0 = (int)((unsigned)btid0 / 147u);

  { // ---- phase 1: per-task setup (one thread per task) ----
    int tid = btid0 + tx;
    unsigned p = (unsigned)tid / 147u;
    int nb = tid - (int)(p * 147u);
    int t = (int)(p >> 12), hw = (int)(p & 4095u);
    int h = hw >> 6, w = hw & 63;
    int slot = nb / 49;
    int rr = nb - slot * 49;
    int a = rr / 7, b = rr - a * 7;
    int tp = t, di = 0, dj = 0;
    if (slot > 0) {
      int si = slot - 1;
      di = (int)rintf(flows[(size_t)((t * 2 + si) * 2 + 0) * 4096 + hw]);
      dj = (int)rintf(flows[(size_t)((t * 2 + si) * 2 + 1) * 4096 + hw]);
      tp = (slot == 1) ? ((t + 1 < TT_) ? t + 1 : t - 2)
                       : ((t - 1 >= 0)  ? t - 1 : t + 2);
    }
    int li = reflect64(h + di + a - 3);
    int lj = reflect64(w + dj + b - 3);
    int kidx = (tp << 12) + (li << 6) + lj;           // < 2^15
    int pixloc = (int)p - p0;                          // 0..2
    s_info[tx] = kidx | (pixloc << 20);
    s_flow[tx * 3 + 0] = (float)(tp - t);
    s_flow[tx * 3 + 1] = (float)(li - h);
    s_flow[tx * 3 + 2] = (float)(lj - w);
  }
  if (tx < 96) { // ---- q staging: 3 pixels x 512B, transposed chunk layout ----
    int pix = tx >> 5, s = tx & 31;                    // s: 16B slice of q vector
    int p = p0 + pix; if (p > NPIX - 1) p = NPIX - 1;
    half8 v = *(const half8*)(qws + (size_t)p * 256 + s * 8);
    ((half8*)s_q)[(pix * 4 + (s & 3)) * 8 + (s >> 2)] = v;  // [pix][c][head]
  }
  __syncthreads();

  // ---- phase 2 ----
  int lane = tx & 63, wv = tx >> 6;
  int j = lane & 7, g = lane >> 3;
  const float scale = 0.17677669529663687f;            // 32^-0.5
#pragma unroll
  for (int it = 0; it < 8; it++) {
    int tb = wv * 64 + it * 8 + g;
    int info = s_info[tb];
    int kidx = info & 0xFFFFF;
    int pixloc = info >> 20;
    const _Float16* kv = kws + (size_t)kidx * 256 + j * 32;  // head j, one 64B line
    float s = 0.f;
#pragma unroll
    for (int c = 0; c < 4; c++) {
      half8 k8 = *(const half8*)(kv + c * 8);
      half8 q8 = ((const half8*)s_q)[(pixloc * 4 + c) * 8 + j];
#pragma unroll
      for (int u = 0; u < 8; u += 2) {
        h2 ka = { k8[u], k8[u + 1] };
        h2 qa = { q8[u], q8[u + 1] };
        s = dot2f(ka, qa, s);
      }
    }
    s_attn[j * 260 + tb] = s * scale;
  }
  __syncthreads();

  // ---- coalesced stores from LDS ----
  const float4* sa4 = (const float4*)s_attn;           // row stride 65 float4
#pragma unroll
  for (int o = 0; o < 2; o++) {
    int gg = tx + o * 256;                             // 0..511
    int hh = gg >> 6, idx = gg & 63;
    ((float4*)(out + (size_t)hh * NTASK + btid0))[idx] = sa4[hh * 65 + idx];
  }
  float* fo = out + (size_t)HEADS_ * NTASK;
  const float4* sf4 = (const float4*)s_flow;
#pragma unroll
  for (int o = 0; o < 6; o++) {
    int gg = tx + o * 256;                             // 0..1535
    int hh = gg / 192, idx = gg - hh * 192;
    ((float4*)(fo + (size_t)hh * NTASK * 3 + (size_t)btid0 * 3))[idx] = sf4[idx];
  }
}

extern "C" void kernel_launch(void* const* d_in, const int* in_sizes, int n_in,
                              void* d_out, int out_size, void* d_ws, size_t ws_size,
                              hipStream_t stream) {
  const float* x     = (const float*)d_in[0];   // (8,64,64,256) f32
  const float* flows = (const float*)d_in[1];   // (1,8,2,2,64,64) f32
  const float* wqk   = (const float*)d_in[2];   // (512,256) f32
  float* out = (float*)d_out;

  _Float16* qws = (_Float16*)d_ws;                       // 32768*256 f16
  _Float16* kws = qws + (size_t)NPIX * 256;              // 32768*256 f16
  _Float16* Ap  = kws + (size_t)NPIX * 256;              // 33280*256 f16 fragments

  prepack<<<dim3(ROWS_ * 32 / 256), dim3(256), 0, stream>>>(x, wqk, Ap);
  qk_gemm<<<dim3(4096), dim3(256), 0, stream>>>(Ap, qws, kws);
  attn_kernel<<<dim3(NTASK / 256), dim3(256), 0, stream>>>(flows, qws, kws, out);
}